// Round 1
// baseline (1267.768 us; speedup 1.0000x reference)
//
#include <hip/hip_runtime.h>
#include <cstdint>
#include <cstddef>

// Problem dims (TemporalLSTM_77455440216810)
#define IDIM 128   // INPUT_DIM
#define HS   256   // HIDDEN
#define SEQL 512   // SEQ
#define TOUT 24    // OUT (scan steps)
#define TMP  64    // TEMP
#define NB   512   // B
#define G4   1024  // 4*HS

typedef unsigned short u16;
typedef unsigned int   u32;
typedef __attribute__((ext_vector_type(8))) short bf16x8;  // 8 bf16 = 4 VGPR (MFMA A/B frag)
typedef __attribute__((ext_vector_type(4))) float f32x4;   // MFMA C/D frag

// ---- LDS layout (bytes). Total 155776 <= 163840 (160 KiB/CU) -> 1 WG/CU. ----
#define OFF_HFRAG 0        // 512x128 bf16, MFMA-A fragment order: 8192 chunks x 16B
#define OFF_WAG   131072   // 16 KiB: Wa_t bf16 B-frags (P0/P1)  UNION  gatep[4][1024] f32 (P4/P5)
#define OFF_E     147456   // e[512] f32
#define OFF_CUAP  149504   // cua partials [8][64] f32
#define OFF_CTXP  151552   // ctx partials [2][128] f32
#define OFF_H     152576   // h[256] f32
#define OFF_C     153600   // c[256] f32
#define OFF_CTX   154624   // ctx[128] f32
#define OFF_CUABA 155136   // cua+ba [64] f32
#define OFF_VA    155392   // Va_t [64] f32
#define OFF_RED   155648   // reduction scratch [16] f32
#define OFF_Y     155712   // y scalar
#define SMEM_BYTES 155776

__device__ __forceinline__ u16 f2bf(float f) {            // RNE f32->bf16
  union { float f; u32 u; } v; v.f = f;
  u32 r = v.u + 0x7FFFu + ((v.u >> 16) & 1u);
  return (u16)(r >> 16);
}
__device__ __forceinline__ float bf2f(u16 s) {
  union { u32 u; float f; } v; v.u = ((u32)s) << 16; return v.f;
}
__device__ __forceinline__ float bflo(u32 u) {            // low bf16 of packed dword
  union { u32 u; float f; } v; v.u = u << 16; return v.f;
}
__device__ __forceinline__ float bfhi(u32 u) {
  union { u32 u; float f; } v; v.u = u & 0xFFFF0000u; return v.f;
}
// Pade(3/2) tanh, clamped. |err|<=0.024; used only for attention scores where the
// Va-dot + softmax attenuates it to ~3e-3 (<< 1.89e-2 threshold).
__device__ __forceinline__ float tanh_fast(float x) {
  float x2 = x * x;
  float r = x * (27.0f + x2) * __builtin_amdgcn_rcpf(27.0f + 9.0f * x2);
  return fminf(fmaxf(r, -1.0f), 1.0f);
}
// Accurate (~1e-6 rel) activations for the LSTM cell (output-facing).
__device__ __forceinline__ float sigmoid_acc(float x) {
  return __builtin_amdgcn_rcpf(1.0f + __builtin_exp2f(-1.4426950408889634f * x));
}
__device__ __forceinline__ float tanh_acc(float x) {
  return 1.0f - 2.0f * __builtin_amdgcn_rcpf(1.0f + __builtin_exp2f(2.8853900817779268f * x));
}

__global__ void cvt_bf16_kernel(const float* __restrict__ src, u16* __restrict__ dst, int n) {
  int i = blockIdx.x * blockDim.x + threadIdx.x;
  int stride = gridDim.x * blockDim.x;
  for (; i < n; i += stride) dst[i] = f2bf(src[i]);
}

// Persistent per-b kernel: one workgroup = one batch element, all 24 steps in-kernel.
// WBF=1: gate/attn weights streamed as prep-converted bf16 from ws; WBF=0: fp32 originals.
template <int WBF>
__global__ __launch_bounds__(512, 2) void lstm_attn_kernel(
    const float* __restrict__ H, const float* __restrict__ y0, const float* __restrict__ emb,
    const float* __restrict__ Wa, const float* __restrict__ UaF, const float* __restrict__ ba,
    const float* __restrict__ Va, const float* __restrict__ WF, const float* __restrict__ UF,
    const float* __restrict__ bias, const float* __restrict__ WyF, const float* __restrict__ fcw,
    const float* __restrict__ fcb, const u16* __restrict__ Ubf, const u16* __restrict__ Wbf,
    const u16* __restrict__ Wybf, const u16* __restrict__ Uabf, float* __restrict__ out) {
  const int b = blockIdx.x;
  const int tid = threadIdx.x;
  const int lane = tid & 63;
  const int wv = tid >> 6;
  extern __shared__ char smem[];
  float* eL     = (float*)(smem + OFF_E);
  float* hL     = (float*)(smem + OFF_H);
  float* cL     = (float*)(smem + OFF_C);
  float* ctxL   = (float*)(smem + OFF_CTX);
  float* cuapL  = (float*)(smem + OFF_CUAP);
  float* ctxpL  = (float*)(smem + OFF_CTXP);
  float* cuabaL = (float*)(smem + OFF_CUABA);
  float* vaL    = (float*)(smem + OFF_VA);
  float* redL   = (float*)(smem + OFF_RED);
  float* yL     = (float*)(smem + OFF_Y);
  u32* hfragU   = (u32*)(smem + OFF_HFRAG);
  u32* wagU     = (u32*)(smem + OFF_WAG);
  float* gatepL = (float*)(smem + OFF_WAG);  // union with Wa frags (disjoint phases)

  // ---- one-time: stage H_b into LDS as bf16 MFMA-A fragments ----
  // chunk(l, kq): 8 consecutive d (=K) bf16 for row l, kq = k-octet 0..15.
  // stored at ((mtile*4+kc)*64 + q*16 + lm)*16B with mtile=l>>4, lm=l&15, kc=kq>>2, q=kq&3
  {
    const float* Hb = H + (size_t)b * (SEQL * IDIM);
#pragma unroll 2
    for (int it = 0; it < 16; ++it) {
      int ch = it * 512 + tid;  // 0..8191, coalesced 32B/thread
      int l = ch >> 4, kq = ch & 15;
      const float* src = Hb + l * IDIM + kq * 8;
      float4 a = *(const float4*)src;
      float4 c4 = *(const float4*)(src + 4);
      u32 d0 = (u32)f2bf(a.x) | ((u32)f2bf(a.y) << 16);
      u32 d1 = (u32)f2bf(a.z) | ((u32)f2bf(a.w) << 16);
      u32 d2 = (u32)f2bf(c4.x) | ((u32)f2bf(c4.y) << 16);
      u32 d3 = (u32)f2bf(c4.z) | ((u32)f2bf(c4.w) << 16);
      int mtile = l >> 4, lm = l & 15, kc = kq >> 2, q = kq & 3;
      *(uint4*)(hfragU + (size_t)(((mtile * 4 + kc) * 64 + q * 16 + lm) * 4)) =
          make_uint4(d0, d1, d2, d3);
    }
  }
  // init carries
  if (tid < 256) {
    hL[tid] = emb[(size_t)b * 512 + tid];
    cL[tid] = emb[(size_t)b * 512 + 256 + tid];
  }
  if (tid == 256) yL[0] = y0[b];
  __syncthreads();

#pragma unroll 1
  for (int t = 0; t < TOUT; ++t) {
    // ================= P0: stage Wa_t B-frags to LDS + cUa partials =================
#pragma unroll
    for (int cc = 0; cc < 2; ++cc) {
      int ch = tid * 2 + cc;  // 0..1023  = nt*256 + kc*64 + q*16 + lm
      int lm = ch & 15, q = (ch >> 4) & 3, kc = (ch >> 6) & 3, nt = ch >> 8;
      int n = nt * 16 + lm;
      u32 dw[4];
#pragma unroll
      for (int p = 0; p < 4; ++p) {
        int k0 = kc * 32 + q * 8 + p * 2;
        float f0 = Wa[((size_t)k0 * TOUT + t) * TMP + n];
        float f1 = Wa[((size_t)(k0 + 1) * TOUT + t) * TMP + n];
        dw[p] = (u32)f2bf(f0) | ((u32)f2bf(f1) << 16);
      }
      *(uint4*)(wagU + (size_t)ch * 4) = make_uint4(dw[0], dw[1], dw[2], dw[3]);
    }
    {  // cUa_j partials: j = tid&63, d-slice = tid>>6
      int j = tid & 63, part = tid >> 6;
      float s = 0.f;
#pragma unroll 4
      for (int i = 0; i < 32; ++i) {
        int d = part * 32 + i;
        float uv = WBF ? bf2f(Uabf[((size_t)d * TOUT + t) * TMP + j])
                       : UaF[((size_t)d * TOUT + t) * TMP + j];
        s += cL[d] * uv;
      }
      cuapL[part * 64 + j] = s;
    }
    __syncthreads();
    if (tid < 64) {
      float s = 0.f;
#pragma unroll
      for (int p = 0; p < 8; ++p) s += cuapL[p * 64 + tid];
      cuabaL[tid] = s + ba[t * TMP + tid];
      vaL[tid] = Va[tid * TOUT + t];
    }
    __syncthreads();

    // ================= P1: e-pass, T = H_b @ Wa_t via MFMA, then tanh/Va reduce ====
    {
      int lm = lane & 15, q = lane >> 4;
      float cb[4], vv[4];
#pragma unroll
      for (int nt = 0; nt < 4; ++nt) {
        cb[nt] = cuabaL[nt * 16 + lm];
        vv[nt] = vaL[nt * 16 + lm];
      }
      bf16x8 bfr[4][4];
#pragma unroll
      for (int nt = 0; nt < 4; ++nt)
#pragma unroll
        for (int kc = 0; kc < 4; ++kc)
          bfr[nt][kc] = *(bf16x8*)(smem + OFF_WAG + (size_t)(((nt * 4 + kc) * 64 + lane) * 16));
#pragma unroll
      for (int mm = 0; mm < 4; ++mm) {
        int mtile = wv * 4 + mm;
        f32x4 acc0 = 0, acc1 = 0, acc2 = 0, acc3 = 0;
#pragma unroll
        for (int kc = 0; kc < 4; ++kc) {
          bf16x8 af = *(bf16x8*)(smem + OFF_HFRAG + (size_t)((((mtile * 4 + kc) * 64) + lane) * 16));
          acc0 = __builtin_amdgcn_mfma_f32_16x16x32_bf16(af, bfr[0][kc], acc0, 0, 0, 0);
          acc1 = __builtin_amdgcn_mfma_f32_16x16x32_bf16(af, bfr[1][kc], acc1, 0, 0, 0);
          acc2 = __builtin_amdgcn_mfma_f32_16x16x32_bf16(af, bfr[2][kc], acc2, 0, 0, 0);
          acc3 = __builtin_amdgcn_mfma_f32_16x16x32_bf16(af, bfr[3][kc], acc3, 0, 0, 0);
        }
        // C/D layout (m89): col j = nt*16 + (lane&15), row = mtile*16 + (lane>>4)*4 + r
#pragma unroll
        for (int r = 0; r < 4; ++r) {
          float v = tanh_fast(acc0[r] + cb[0]) * vv[0] + tanh_fast(acc1[r] + cb[1]) * vv[1] +
                    tanh_fast(acc2[r] + cb[2]) * vv[2] + tanh_fast(acc3[r] + cb[3]) * vv[3];
          v += __shfl_xor(v, 1);
          v += __shfl_xor(v, 2);
          v += __shfl_xor(v, 4);
          v += __shfl_xor(v, 8);
          if (lm == 0) eL[mtile * 16 + q * 4 + r] = v;
        }
      }
    }
    __syncthreads();

    // ================= P2: softmax over e (logits = e/16) =================
    float invden;
    {
      float v = eL[tid];
      float m = v;
#pragma unroll
      for (int msk = 1; msk <= 32; msk <<= 1) m = fmaxf(m, __shfl_xor(m, msk));
      if (lane == 0) redL[wv] = m;
      __syncthreads();
      float M = redL[0];
#pragma unroll
      for (int p = 1; p < 8; ++p) M = fmaxf(M, redL[p]);
      float pv = __builtin_exp2f((v - M) * 0.0901684400347379f);  // (1/16)*log2(e)
      eL[tid] = pv;
      float s = pv;
#pragma unroll
      for (int msk = 1; msk <= 32; msk <<= 1) s += __shfl_xor(s, msk);
      if (lane == 0) redL[8 + wv] = s;
      __syncthreads();
      float den = 0.f;
#pragma unroll
      for (int p = 0; p < 8; ++p) den += redL[8 + p];
      invden = __builtin_amdgcn_rcpf(den);
    }

    // ================= P3: ctx_d = (1/den) * sum_l p_l * H[l][d] =================
    {
      int lsub = tid & 15, dch = (tid >> 4) & 15, half = tid >> 8;
      int kc = dch >> 2, q = dch & 3;
      f32x4 a0 = 0, a1 = 0;
#pragma unroll 4
      for (int i = 0; i < 16; ++i) {
        int mt = half * 16 + i;
        int l = mt * 16 + lsub;
        uint4 hv = *(uint4*)(smem + OFF_HFRAG + (size_t)((((mt * 4 + kc) * 64) + q * 16 + lsub) * 16));
        float p = eL[l];
        a0.x += p * bflo(hv.x); a0.y += p * bfhi(hv.x);
        a0.z += p * bflo(hv.y); a0.w += p * bfhi(hv.y);
        a1.x += p * bflo(hv.z); a1.y += p * bfhi(hv.z);
        a1.z += p * bflo(hv.w); a1.w += p * bfhi(hv.w);
      }
#pragma unroll
      for (int msk = 1; msk <= 8; msk <<= 1) {
        a0.x += __shfl_xor(a0.x, msk); a0.y += __shfl_xor(a0.y, msk);
        a0.z += __shfl_xor(a0.z, msk); a0.w += __shfl_xor(a0.w, msk);
        a1.x += __shfl_xor(a1.x, msk); a1.y += __shfl_xor(a1.y, msk);
        a1.z += __shfl_xor(a1.z, msk); a1.w += __shfl_xor(a1.w, msk);
      }
      if (lsub == 0) {
        *(f32x4*)&ctxpL[half * 128 + dch * 8] = a0;
        *(f32x4*)&ctxpL[half * 128 + dch * 8 + 4] = a1;
      }
    }
    __syncthreads();
    if (tid < 128) ctxL[tid] = (ctxpL[tid] + ctxpL[128 + tid]) * invden;
    __syncthreads();

    // ================= P4: gates partial GEMV (the L2 weight stream) =================
    {
      int gc = tid & 127, dpart = tid >> 7;
      const int gbase = gc * 8;
      f32x4 g0 = 0, g1 = 0;
#pragma unroll 4
      for (int i = 0; i < 32; ++i) {  // ctx @ W_t slice
        int d = dpart * 32 + i;
        float cv = ctxL[d];
        if (WBF) {
          uint4 w4 = *(const uint4*)(Wbf + ((size_t)(d * TOUT + t)) * G4 + gbase);
          g0.x += cv * bflo(w4.x); g0.y += cv * bfhi(w4.x);
          g0.z += cv * bflo(w4.y); g0.w += cv * bfhi(w4.y);
          g1.x += cv * bflo(w4.z); g1.y += cv * bfhi(w4.z);
          g1.z += cv * bflo(w4.w); g1.w += cv * bfhi(w4.w);
        } else {
          const float4* p4 = (const float4*)(WF + ((size_t)(d * TOUT + t)) * G4 + gbase);
          float4 wa = p4[0], wb = p4[1];
          g0.x += cv * wa.x; g0.y += cv * wa.y; g0.z += cv * wa.z; g0.w += cv * wa.w;
          g1.x += cv * wb.x; g1.y += cv * wb.y; g1.z += cv * wb.z; g1.w += cv * wb.w;
        }
      }
#pragma unroll 4
      for (int i = 0; i < 64; ++i) {  // h @ U_t slice
        int d = dpart * 64 + i;
        float hv = hL[d];
        if (WBF) {
          uint4 u4 = *(const uint4*)(Ubf + ((size_t)(d * TOUT + t)) * G4 + gbase);
          g0.x += hv * bflo(u4.x); g0.y += hv * bfhi(u4.x);
          g0.z += hv * bflo(u4.y); g0.w += hv * bfhi(u4.y);
          g1.x += hv * bflo(u4.z); g1.y += hv * bfhi(u4.z);
          g1.z += hv * bflo(u4.w); g1.w += hv * bfhi(u4.w);
        } else {
          const float4* p4 = (const float4*)(UF + ((size_t)(d * TOUT + t)) * G4 + gbase);
          float4 ua = p4[0], ub = p4[1];
          g0.x += hv * ua.x; g0.y += hv * ua.y; g0.z += hv * ua.z; g0.w += hv * ua.w;
          g1.x += hv * ub.x; g1.y += hv * ub.y; g1.z += hv * ub.z; g1.w += hv * ub.w;
        }
      }
      *(f32x4*)&gatepL[dpart * G4 + gbase] = g0;
      *(f32x4*)&gatepL[dpart * G4 + gbase + 4] = g1;
    }
    __syncthreads();

    // ================= P5: gate reduce + LSTM cell + y =================
    float ypart = 0.f;
    if (tid < 256) {
      int hc = tid;
      float gv[4];
#pragma unroll
      for (int gi = 0; gi < 4; ++gi) {
        int col = hc + gi * 256;
        float s = gatepL[col] + gatepL[G4 + col] + gatepL[2 * G4 + col] + gatepL[3 * G4 + col];
        s += bias[(size_t)t * G4 + col];
        float wyv = WBF ? bf2f(Wybf[t * G4 + col]) : WyF[t * G4 + col];
        s += yL[0] * wyv;  // reads y_{t-1} (rewritten only after the next barrier)
        gv[gi] = s;
      }
      float ig = sigmoid_acc(gv[0]);
      float fg = sigmoid_acc(gv[1]);
      float gg = tanh_acc(gv[2]);
      float og = sigmoid_acc(gv[3]);
      float cn = fg * cL[hc] + ig * gg;
      float hn = og * tanh_acc(cn);
      cL[hc] = cn;
      hL[hc] = hn;
      out[12288 + ((size_t)b * TOUT + t) * HS + hc] = hn;  // hidden_seq[b][t][hc]
      ypart = hn * fcw[t * HS + hc];
    }
#pragma unroll
    for (int msk = 1; msk <= 32; msk <<= 1) ypart += __shfl_xor(ypart, msk);
    if (tid < 256 && lane == 0) redL[wv] = ypart;
    __syncthreads();
    if (tid == 0) {
      float y = redL[0] + redL[1] + redL[2] + redL[3] + fcb[t];
      yL[0] = y;
      out[(size_t)b * TOUT + t] = y;  // y_out[b][t]
    }
    __syncthreads();
  }
}

extern "C" void kernel_launch(void* const* d_in, const int* in_sizes, int n_in, void* d_out,
                              int out_size, void* d_ws, size_t ws_size, hipStream_t stream) {
  const float* H    = (const float*)d_in[0];
  const float* y0   = (const float*)d_in[1];
  const float* emb  = (const float*)d_in[2];
  const float* Wa   = (const float*)d_in[3];
  const float* Ua   = (const float*)d_in[4];
  const float* ba   = (const float*)d_in[5];
  const float* Va   = (const float*)d_in[6];
  const float* W    = (const float*)d_in[7];
  const float* U    = (const float*)d_in[8];
  const float* bias = (const float*)d_in[9];
  const float* Wy   = (const float*)d_in[10];
  const float* fcw  = (const float*)d_in[11];
  const float* fcb  = (const float*)d_in[12];
  float* out = (float*)d_out;

  const size_t nU = (size_t)HS * TOUT * G4;    // 6291456
  const size_t nW = (size_t)IDIM * TOUT * G4;  // 3145728
  const size_t nWy = (size_t)TOUT * G4;        // 24576
  const size_t nUa = (size_t)HS * TOUT * TMP;  // 393216
  const size_t need = (nU + nW + nWy + nUa) * sizeof(u16);
  const bool usebf = (d_ws != nullptr) && (ws_size >= need);

  u16* Ubf = (u16*)d_ws;
  u16* Wbf = Ubf + nU;
  u16* Wybf = Wbf + nW;
  u16* Uabf = Wybf + nWy;

  if (usebf) {  // prep: fp32 -> bf16 weight conversion (re-run every call; ws is re-poisoned)
    cvt_bf16_kernel<<<2048, 256, 0, stream>>>(U, Ubf, (int)nU);
    cvt_bf16_kernel<<<1024, 256, 0, stream>>>(W, Wbf, (int)nW);
    cvt_bf16_kernel<<<96, 256, 0, stream>>>(Wy, Wybf, (int)nWy);
    cvt_bf16_kernel<<<256, 256, 0, stream>>>(Ua, Uabf, (int)nUa);
  }

  hipFuncSetAttribute((const void*)lstm_attn_kernel<1>,
                      hipFuncAttributeMaxDynamicSharedMemorySize, SMEM_BYTES);
  hipFuncSetAttribute((const void*)lstm_attn_kernel<0>,
                      hipFuncAttributeMaxDynamicSharedMemorySize, SMEM_BYTES);

  if (usebf) {
    lstm_attn_kernel<1><<<NB, 512, SMEM_BYTES, stream>>>(H, y0, emb, Wa, Ua, ba, Va, W, U, bias,
                                                         Wy, fcw, fcb, Ubf, Wbf, Wybf, Uabf, out);
  } else {
    lstm_attn_kernel<0><<<NB, 512, SMEM_BYTES, stream>>>(H, y0, emb, Wa, Ua, ba, Va, W, U, bias,
                                                         Wy, fcw, fcb, Ubf, Wbf, Wybf, Uabf, out);
  }
}

// Round 2
// 1115.956 us; speedup vs baseline: 1.1360x; 1.1360x over previous
//
#include <hip/hip_runtime.h>
#include <hip/hip_fp8.h>
#include <cstdint>
#include <cstddef>

// Problem dims (TemporalLSTM_77455440216810)
#define IDIM 128   // INPUT_DIM
#define HS   256   // HIDDEN
#define SEQL 512   // SEQ
#define TOUT 24    // OUT (scan steps)
#define TMP  64    // TEMP
#define NB   512   // B
#define G4   1024  // 4*HS

typedef unsigned short u16;
typedef unsigned int   u32;
typedef __attribute__((ext_vector_type(4))) float f32x4;   // MFMA C/D frag

// ---- LDS layout (bytes). Total 161744 <= 163840. 1 WG (1024 thr) / CU. ----
#define OFF_HFRAG 0        // 2 x (512x128 fp8) MFMA-A frags: 2 x 65536
#define OFF_GATEP 131072   // 16384: gate partials u32[2b][4p][512] (bf16 pairs)
                           //        UNION Wa fp8 B-frags (8192) -- disjoint phases
#define OFF_E     147456   // e[2][512] f32
#define OFF_CUAP  151552   // cua partials [2][4][64] f32
#define OFF_CTXP  153600   // ctx partials [2][2][128] f32
#define OFF_H     155648   // h[2][256] f32
#define OFF_C     157696   // c[2][256] f32
#define OFF_CTX   159744   // ctx[2][128] f32
#define OFF_CUABA 160768   // cua+ba [2][64] f32
#define OFF_VA    161280   // Va_t [64] f32
#define OFF_RED   161536   // reduction scratch [2][24] f32
#define OFF_Y     161728   // y[2]
#define OFF_INVD  161736   // invden[2]
#define SMEM_BYTES 161744

__device__ __forceinline__ u16 f2bf(float f) {            // RNE f32->bf16
  union { float f; u32 u; } v; v.f = f;
  u32 r = v.u + 0x7FFFu + ((v.u >> 16) & 1u);
  return (u16)(r >> 16);
}
__device__ __forceinline__ float bf2f(u16 s) {
  union { u32 u; float f; } v; v.u = ((u32)s) << 16; return v.f;
}
__device__ __forceinline__ float bflo(u32 u) {
  union { u32 u; float f; } v; v.u = u << 16; return v.f;
}
__device__ __forceinline__ float bfhi(u32 u) {
  union { u32 u; float f; } v; v.u = u & 0xFFFF0000u; return v.f;
}
__device__ __forceinline__ u32 pkbf(float a, float b) {
  return (u32)f2bf(a) | ((u32)f2bf(b) << 16);
}
// fp8 e4m3 (OCP) pack/unpack
__device__ __forceinline__ u32 pk4_fp8(float a, float b, float c, float d) {
#if __has_builtin(__builtin_amdgcn_cvt_pk_fp8_f32)
  u32 v = (u32)__builtin_amdgcn_cvt_pk_fp8_f32(a, b, 0, false);
  v = (u32)__builtin_amdgcn_cvt_pk_fp8_f32(c, d, (int)v, true);
  return v;
#else
  __hip_fp8_e4m3 x(a), y(b), z(c), w(d);
  return (u32)x.__x | ((u32)y.__x << 8) | ((u32)z.__x << 16) | ((u32)w.__x << 24);
#endif
}
template <int S>
__device__ __forceinline__ float fp8_f32(u32 v) {
#if __has_builtin(__builtin_amdgcn_cvt_f32_fp8)
  return __builtin_amdgcn_cvt_f32_fp8((int)v, S);
#else
  __hip_fp8_e4m3 x; x.__x = (unsigned char)(v >> (8 * S)); return (float)x;
#endif
}
// Pade(3/2) tanh for attention scores (error attenuated by Va-dot + /16 + softmax)
__device__ __forceinline__ float tanh_fast(float x) {
  float x2 = x * x;
  float r = x * (27.0f + x2) * __builtin_amdgcn_rcpf(27.0f + 9.0f * x2);
  return fminf(fmaxf(r, -1.0f), 1.0f);
}
__device__ __forceinline__ float sigmoid_acc(float x) {
  return __builtin_amdgcn_rcpf(1.0f + __builtin_exp2f(-1.4426950408889634f * x));
}
__device__ __forceinline__ float tanh_acc(float x) {
  return 1.0f - 2.0f * __builtin_amdgcn_rcpf(1.0f + __builtin_exp2f(2.8853900817779268f * x));
}

__global__ void cvt_bf16_kernel(const float* __restrict__ src, u16* __restrict__ dst, int n) {
  int i = blockIdx.x * blockDim.x + threadIdx.x;
  int stride = gridDim.x * blockDim.x;
  for (; i < n; i += stride) dst[i] = f2bf(src[i]);
}

// Persistent kernel: one WG = TWO batch elements (bg0, bg0+1), all 24 steps.
// H in LDS as fp8 MFMA-A frags (64 KB/b). Weights loaded once per dword and
// used for both b's -> halves the L2->CU weight stream vs 1 b/WG.
template <int WBF>
__global__ __launch_bounds__(1024, 4) void lstm_attn_kernel(
    const float* __restrict__ H, const float* __restrict__ y0, const float* __restrict__ emb,
    const float* __restrict__ Wa, const float* __restrict__ UaF, const float* __restrict__ ba,
    const float* __restrict__ Va, const float* __restrict__ WF, const float* __restrict__ UF,
    const float* __restrict__ bias, const float* __restrict__ WyF, const float* __restrict__ fcw,
    const float* __restrict__ fcb, const u16* __restrict__ Ubf, const u16* __restrict__ Wbf,
    const u16* __restrict__ Wybf, const u16* __restrict__ Uabf, float* __restrict__ out) {
  const int bg0 = blockIdx.x * 2;
  const int tid = threadIdx.x;
  const int lane = tid & 63;
  const int wv = tid >> 6;  // 0..15
  extern __shared__ char smem[];
  float* eL     = (float*)(smem + OFF_E);
  float* hL     = (float*)(smem + OFF_H);
  float* cL     = (float*)(smem + OFF_C);
  float* ctxL   = (float*)(smem + OFF_CTX);
  float* cuapL  = (float*)(smem + OFF_CUAP);
  float* ctxpL  = (float*)(smem + OFF_CTXP);
  float* cuabaL = (float*)(smem + OFF_CUABA);
  float* vaL    = (float*)(smem + OFF_VA);
  float* redL   = (float*)(smem + OFF_RED);
  float* yL     = (float*)(smem + OFF_Y);
  float* invdL  = (float*)(smem + OFF_INVD);
  u32* gatepU   = (u32*)(smem + OFF_GATEP);

  // ---- one-time: stage H for both b's into LDS as fp8 MFMA-A fragments ----
  // A-frag (16x16x32 family): m = lane&15, k = (lane>>4)*8 + j.
  // chunk (b, l, oct): 8 fp8 at  b*65536 + ((mtile*4+kc)*64 + q*16 + lm)*8
  //   mtile=l>>4, lm=l&15, kc=oct>>2, q=oct&3.
#pragma unroll 2
  for (int it = 0; it < 16; ++it) {
    int ch = it * 1024 + tid;           // 0..16383
    int bl = ch >> 13;                  // which b
    int c2 = ch & 8191;
    int l = c2 >> 4, oct = c2 & 15;
    const float* src = H + (size_t)(bg0 + bl) * (SEQL * IDIM) + l * IDIM + oct * 8;
    float4 a = *(const float4*)src;
    float4 c4 = *(const float4*)(src + 4);
    u32 lo = pk4_fp8(a.x, a.y, a.z, a.w);
    u32 hi = pk4_fp8(c4.x, c4.y, c4.z, c4.w);
    int mtile = l >> 4, lm = l & 15, kc = oct >> 2, q = oct & 3;
    *(uint2*)(smem + OFF_HFRAG + (size_t)bl * 65536 +
              (size_t)(((mtile * 4 + kc) * 64 + q * 16 + lm)) * 8) = make_uint2(lo, hi);
  }
  if (tid < 512) {  // carries
    int b = tid >> 8, i = tid & 255;
    hL[b * 256 + i] = emb[(size_t)(bg0 + b) * 512 + i];
    cL[b * 256 + i] = emb[(size_t)(bg0 + b) * 512 + 256 + i];
  }
  if (tid < 2) yL[tid] = y0[bg0 + tid];
  __syncthreads();

#pragma unroll 1
  for (int t = 0; t < TOUT; ++t) {
    // ===== P0: stage Wa_t fp8 B-frags (union w/ gatep) + c@Ua partials =====
    {  // B-frag: n = lane&15, k = (lane>>4)*8+j; frag (nt,kc) at ((nt*4+kc)*64+lane)*8
      int nt = tid >> 8, kc = (tid >> 6) & 3, l6 = tid & 63;
      int lm = l6 & 15, q = l6 >> 4;
      int n = nt * 16 + lm;
      float f[8];
#pragma unroll
      for (int j = 0; j < 8; ++j) {
        int k = kc * 32 + q * 8 + j;
        f[j] = Wa[((size_t)k * TOUT + t) * TMP + n];
      }
      *(uint2*)(smem + OFF_GATEP + (size_t)tid * 8) =
          make_uint2(pk4_fp8(f[0], f[1], f[2], f[3]), pk4_fp8(f[4], f[5], f[6], f[7]));
    }
    if (tid < 128) {  // cUa partials: j2 = j-pair, 4 d-parts, both b's
      int j2 = tid & 31, part = tid >> 5;
      float s00 = 0.f, s01 = 0.f, s10 = 0.f, s11 = 0.f;
#pragma unroll 8
      for (int i = 0; i < 64; ++i) {
        int d = part * 64 + i;
        float u0, u1;
        if (WBF) {
          u32 uu = *(const u32*)(Uabf + ((size_t)d * TOUT + t) * TMP + j2 * 2);
          u0 = bflo(uu); u1 = bfhi(uu);
        } else {
          const float* up = UaF + ((size_t)d * TOUT + t) * TMP + j2 * 2;
          u0 = up[0]; u1 = up[1];
        }
        float c0 = cL[d], c1 = cL[256 + d];
        s00 += c0 * u0; s01 += c0 * u1;
        s10 += c1 * u0; s11 += c1 * u1;
      }
      cuapL[(0 * 4 + part) * 64 + j2 * 2] = s00;
      cuapL[(0 * 4 + part) * 64 + j2 * 2 + 1] = s01;
      cuapL[(1 * 4 + part) * 64 + j2 * 2] = s10;
      cuapL[(1 * 4 + part) * 64 + j2 * 2 + 1] = s11;
    }
    __syncthreads();
    if (tid < 128) {
      int b = tid >> 6, j = tid & 63;
      float s = 0.f;
#pragma unroll
      for (int p = 0; p < 4; ++p) s += cuapL[(b * 4 + p) * 64 + j];
      cuabaL[b * 64 + j] = s + ba[t * TMP + j];
      if (tid < 64) vaL[j] = Va[j * TOUT + t];
    }
    __syncthreads();

    // ===== P1: e-pass  T = H_b @ Wa_t (fp8 MFMA), tanh, Va-dot =====
    {
      const int b = wv >> 3, m8 = wv & 7;
      const int lm = lane & 15, q = lane >> 4;
      float cb[4], vv[4];
#pragma unroll
      for (int nt = 0; nt < 4; ++nt) {
        cb[nt] = cuabaL[b * 64 + nt * 16 + lm];
        vv[nt] = vaL[nt * 16 + lm];
      }
      long bfr[4][4];
#pragma unroll
      for (int nt = 0; nt < 4; ++nt)
#pragma unroll
        for (int kc = 0; kc < 4; ++kc)
          bfr[nt][kc] = *(const long*)(smem + OFF_GATEP + (size_t)(((nt * 4 + kc) * 64 + lane)) * 8);
#pragma unroll
      for (int mm = 0; mm < 4; ++mm) {
        int mtile = m8 * 4 + mm;
        f32x4 acc0 = 0, acc1 = 0, acc2 = 0, acc3 = 0;
#pragma unroll
        for (int kc = 0; kc < 4; ++kc) {
          long af = *(const long*)(smem + OFF_HFRAG + (size_t)b * 65536 +
                                   (size_t)(((mtile * 4 + kc) * 64 + lane)) * 8);
          acc0 = __builtin_amdgcn_mfma_f32_16x16x32_fp8_fp8(af, bfr[0][kc], acc0, 0, 0, 0);
          acc1 = __builtin_amdgcn_mfma_f32_16x16x32_fp8_fp8(af, bfr[1][kc], acc1, 0, 0, 0);
          acc2 = __builtin_amdgcn_mfma_f32_16x16x32_fp8_fp8(af, bfr[2][kc], acc2, 0, 0, 0);
          acc3 = __builtin_amdgcn_mfma_f32_16x16x32_fp8_fp8(af, bfr[3][kc], acc3, 0, 0, 0);
        }
        // C/D: col = nt*16 + (lane&15), row = mtile*16 + (lane>>4)*4 + r
#pragma unroll
        for (int r = 0; r < 4; ++r) {
          float v = tanh_fast(acc0[r] + cb[0]) * vv[0] + tanh_fast(acc1[r] + cb[1]) * vv[1] +
                    tanh_fast(acc2[r] + cb[2]) * vv[2] + tanh_fast(acc3[r] + cb[3]) * vv[3];
          v += __shfl_xor(v, 1);
          v += __shfl_xor(v, 2);
          v += __shfl_xor(v, 4);
          v += __shfl_xor(v, 8);
          if (lm == 0) eL[b * 512 + mtile * 16 + q * 4 + r] = v;
        }
      }
    }
    __syncthreads();

    // ===== P2: per-b softmax (logits = e/16) =====
    {
      int b = tid >> 9;
      int w8 = (tid >> 6) & 7;
      float v = eL[tid];
      float m = v;
#pragma unroll
      for (int msk = 1; msk <= 32; msk <<= 1) m = fmaxf(m, __shfl_xor(m, msk));
      if (lane == 0) redL[b * 24 + w8] = m;
      __syncthreads();
      float M = redL[b * 24];
#pragma unroll
      for (int p = 1; p < 8; ++p) M = fmaxf(M, redL[b * 24 + p]);
      float pv = __builtin_exp2f((v - M) * 0.0901684400347379f);  // (1/16)*log2(e)
      eL[tid] = pv;
      float s = pv;
#pragma unroll
      for (int msk = 1; msk <= 32; msk <<= 1) s += __shfl_xor(s, msk);
      if (lane == 0) redL[b * 24 + 8 + w8] = s;
      __syncthreads();
      float den = 0.f;
#pragma unroll
      for (int p = 0; p < 8; ++p) den += redL[b * 24 + 8 + p];
      if ((tid & 511) == 0) invdL[b] = __builtin_amdgcn_rcpf(den);
    }

    // ===== P3: ctx_d = sum_l p_l H[l][d] (fp8 H from LDS) =====
    {
      int b = tid >> 9, stid = tid & 511;
      int lsub = stid & 15, dch = (stid >> 4) & 15, half = stid >> 8;
      int kc = dch >> 2, q = dch & 3;
      const char* hbase = smem + OFF_HFRAG + (size_t)b * 65536;
      float a[8] = {0.f, 0.f, 0.f, 0.f, 0.f, 0.f, 0.f, 0.f};
#pragma unroll 4
      for (int i = 0; i < 16; ++i) {
        int mt = half * 16 + i;
        int l = mt * 16 + lsub;
        uint2 hv = *(const uint2*)(hbase + (size_t)(((mt * 4 + kc) * 64 + q * 16 + lsub)) * 8);
        float p = eL[b * 512 + l];
        a[0] += p * fp8_f32<0>(hv.x); a[1] += p * fp8_f32<1>(hv.x);
        a[2] += p * fp8_f32<2>(hv.x); a[3] += p * fp8_f32<3>(hv.x);
        a[4] += p * fp8_f32<0>(hv.y); a[5] += p * fp8_f32<1>(hv.y);
        a[6] += p * fp8_f32<2>(hv.y); a[7] += p * fp8_f32<3>(hv.y);
      }
#pragma unroll
      for (int msk = 1; msk <= 8; msk <<= 1)
#pragma unroll
        for (int j = 0; j < 8; ++j) a[j] += __shfl_xor(a[j], msk);
      if (lsub == 0) {
        float* dst = &ctxpL[b * 256 + half * 128 + dch * 8];
#pragma unroll
        for (int j = 0; j < 8; ++j) dst[j] = a[j];
      }
    }
    __syncthreads();
    if (tid < 256) {
      int b = tid >> 7, d = tid & 127;
      ctxL[b * 128 + d] = (ctxpL[b * 256 + d] + ctxpL[b * 256 + 128 + d]) * invdL[b];
    }
    __syncthreads();

    // ===== P4: gates partial GEMV — each weight dword used for BOTH b's =====
    {
      int gc = tid & 255, dpart = tid >> 8;
      const int c0 = gc * 4;
      float g0[4] = {0.f, 0.f, 0.f, 0.f};  // b0 cols c0..c0+3
      float g1[4] = {0.f, 0.f, 0.f, 0.f};  // b1
      // ctx @ W_t  (d = dpart*32 + 0..31)
      {
        const u16* wp = Wbf + ((size_t)(dpart * 32) * TOUT + t) * G4 + c0;
        const float* wpf = WF + ((size_t)(dpart * 32) * TOUT + t) * G4 + c0;
#pragma unroll 2
        for (int i4 = 0; i4 < 8; ++i4) {
          float4 cv0 = *(const float4*)&ctxL[dpart * 32 + i4 * 4];
          float4 cv1 = *(const float4*)&ctxL[128 + dpart * 32 + i4 * 4];
#pragma unroll
          for (int j4 = 0; j4 < 4; ++j4) {
            float w0, w1, w2, w3;
            if (WBF) {
              uint2 w4 = *(const uint2*)wp;
              w0 = bflo(w4.x); w1 = bfhi(w4.x); w2 = bflo(w4.y); w3 = bfhi(w4.y);
              wp += (size_t)TOUT * G4;
            } else {
              float4 wf = *(const float4*)wpf;
              w0 = wf.x; w1 = wf.y; w2 = wf.z; w3 = wf.w;
              wpf += (size_t)TOUT * G4;
            }
            float cc0 = (j4 == 0) ? cv0.x : (j4 == 1) ? cv0.y : (j4 == 2) ? cv0.z : cv0.w;
            float cc1 = (j4 == 0) ? cv1.x : (j4 == 1) ? cv1.y : (j4 == 2) ? cv1.z : cv1.w;
            g0[0] += cc0 * w0; g0[1] += cc0 * w1; g0[2] += cc0 * w2; g0[3] += cc0 * w3;
            g1[0] += cc1 * w0; g1[1] += cc1 * w1; g1[2] += cc1 * w2; g1[3] += cc1 * w3;
          }
        }
      }
      // h @ U_t  (d = dpart*64 + 0..63)
      {
        const u16* up = Ubf + ((size_t)(dpart * 64) * TOUT + t) * G4 + c0;
        const float* upf = UF + ((size_t)(dpart * 64) * TOUT + t) * G4 + c0;
#pragma unroll 2
        for (int i4 = 0; i4 < 16; ++i4) {
          float4 hv0 = *(const float4*)&hL[dpart * 64 + i4 * 4];
          float4 hv1 = *(const float4*)&hL[256 + dpart * 64 + i4 * 4];
#pragma unroll
          for (int j4 = 0; j4 < 4; ++j4) {
            float w0, w1, w2, w3;
            if (WBF) {
              uint2 w4 = *(const uint2*)up;
              w0 = bflo(w4.x); w1 = bfhi(w4.x); w2 = bflo(w4.y); w3 = bfhi(w4.y);
              up += (size_t)TOUT * G4;
            } else {
              float4 wf = *(const float4*)upf;
              w0 = wf.x; w1 = wf.y; w2 = wf.z; w3 = wf.w;
              upf += (size_t)TOUT * G4;
            }
            float hh0 = (j4 == 0) ? hv0.x : (j4 == 1) ? hv0.y : (j4 == 2) ? hv0.z : hv0.w;
            float hh1 = (j4 == 0) ? hv1.x : (j4 == 1) ? hv1.y : (j4 == 2) ? hv1.z : hv1.w;
            g0[0] += hh0 * w0; g0[1] += hh0 * w1; g0[2] += hh0 * w2; g0[3] += hh0 * w3;
            g1[0] += hh1 * w0; g1[1] += hh1 * w1; g1[2] += hh1 * w2; g1[3] += hh1 * w3;
          }
        }
      }
      // bf16-pack partials to LDS: gatepU[b][dpart][gc*2 .. +1]
      *(uint2*)&gatepU[((0 * 4 + dpart) * 512) + gc * 2] =
          make_uint2(pkbf(g0[0], g0[1]), pkbf(g0[2], g0[3]));
      *(uint2*)&gatepU[((1 * 4 + dpart) * 512) + gc * 2] =
          make_uint2(pkbf(g1[0], g1[1]), pkbf(g1[2], g1[3]));
    }
    __syncthreads();

    // ===== P5: gate reduce + LSTM cell + y =====
    float ypart = 0.f;
    int bh = tid >> 8, hc = tid & 255;
    if (tid < 512) {
      float yprev = yL[bh];
      float gv[4];
#pragma unroll
      for (int gi = 0; gi < 4; ++gi) {
        int col = gi * 256 + hc;
        int ci = col >> 1, sel = col & 1;
        float s = 0.f;
#pragma unroll
        for (int p = 0; p < 4; ++p) {
          u32 u = gatepU[(bh * 4 + p) * 512 + ci];
          s += sel ? bfhi(u) : bflo(u);
        }
        s += bias[(size_t)t * G4 + col];
        float wyv = WBF ? bf2f(Wybf[t * G4 + col]) : WyF[t * G4 + col];
        gv[gi] = s + yprev * wyv;
      }
      float ig = sigmoid_acc(gv[0]);
      float fg = sigmoid_acc(gv[1]);
      float gg = tanh_acc(gv[2]);
      float og = sigmoid_acc(gv[3]);
      float cn = fg * cL[bh * 256 + hc] + ig * gg;
      float hn = og * tanh_acc(cn);
      cL[bh * 256 + hc] = cn;
      hL[bh * 256 + hc] = hn;
      out[12288 + ((size_t)(bg0 + bh) * TOUT + t) * HS + hc] = hn;
      ypart = hn * fcw[t * HS + hc];
    }
#pragma unroll
    for (int msk = 1; msk <= 32; msk <<= 1) ypart += __shfl_xor(ypart, msk);
    if (tid < 512 && lane == 0) redL[bh * 24 + 16 + ((tid >> 6) & 3)] = ypart;
    __syncthreads();
    if (tid == 0 || tid == 512) {
      int b2 = tid >> 9;
      float y = redL[b2 * 24 + 16] + redL[b2 * 24 + 17] + redL[b2 * 24 + 18] +
                redL[b2 * 24 + 19] + fcb[t];
      yL[b2] = y;
      out[(size_t)(bg0 + b2) * TOUT + t] = y;
    }
    __syncthreads();
  }
}

extern "C" void kernel_launch(void* const* d_in, const int* in_sizes, int n_in, void* d_out,
                              int out_size, void* d_ws, size_t ws_size, hipStream_t stream) {
  const float* H    = (const float*)d_in[0];
  const float* y0   = (const float*)d_in[1];
  const float* emb  = (const float*)d_in[2];
  const float* Wa   = (const float*)d_in[3];
  const float* Ua   = (const float*)d_in[4];
  const float* ba   = (const float*)d_in[5];
  const float* Va   = (const float*)d_in[6];
  const float* W    = (const float*)d_in[7];
  const float* U    = (const float*)d_in[8];
  const float* bias = (const float*)d_in[9];
  const float* Wy   = (const float*)d_in[10];
  const float* fcw  = (const float*)d_in[11];
  const float* fcb  = (const float*)d_in[12];
  float* out = (float*)d_out;

  const size_t nU = (size_t)HS * TOUT * G4;    // 6291456
  const size_t nW = (size_t)IDIM * TOUT * G4;  // 3145728
  const size_t nWy = (size_t)TOUT * G4;        // 24576
  const size_t nUa = (size_t)HS * TOUT * TMP;  // 393216
  const size_t need = (nU + nW + nWy + nUa) * sizeof(u16);
  const bool usebf = (d_ws != nullptr) && (ws_size >= need);

  u16* Ubf = (u16*)d_ws;
  u16* Wbf = Ubf + nU;
  u16* Wybf = Wbf + nW;
  u16* Uabf = Wybf + nWy;

  if (usebf) {
    cvt_bf16_kernel<<<2048, 256, 0, stream>>>(U, Ubf, (int)nU);
    cvt_bf16_kernel<<<1024, 256, 0, stream>>>(W, Wbf, (int)nW);
    cvt_bf16_kernel<<<96, 256, 0, stream>>>(Wy, Wybf, (int)nWy);
    cvt_bf16_kernel<<<256, 256, 0, stream>>>(Ua, Uabf, (int)nUa);
  }

  hipFuncSetAttribute((const void*)lstm_attn_kernel<1>,
                      hipFuncAttributeMaxDynamicSharedMemorySize, SMEM_BYTES);
  hipFuncSetAttribute((const void*)lstm_attn_kernel<0>,
                      hipFuncAttributeMaxDynamicSharedMemorySize, SMEM_BYTES);

  if (usebf) {
    lstm_attn_kernel<1><<<NB / 2, 1024, SMEM_BYTES, stream>>>(
        H, y0, emb, Wa, Ua, ba, Va, W, U, bias, Wy, fcw, fcb, Ubf, Wbf, Wybf, Uabf, out);
  } else {
    lstm_attn_kernel<0><<<NB / 2, 1024, SMEM_BYTES, stream>>>(
        H, y0, emb, Wa, Ua, ba, Va, W, U, bias, Wy, fcw, fcb, Ubf, Wbf, Wybf, Uabf, out);
  }
}